// Round 5
// baseline (169.683 us; speedup 1.0000x reference)
//
#include <hip/hip_runtime.h>
#include <hip/hip_bf16.h>

// Fourier-KAN, round 5: GEMM M=32768 N=64 K=8192 with on-the-fly A.
// Same math/layout as rounds 2-4 (verified absmax 0.03125):
//   k = i*16 + t*8 + g; mfma_f32_32x32x16_bf16; A/B slot-symmetric k map;
//   C/D col=lane&31, row=(reg&3)+8*(reg>>2)+4*(lane>>5).
// NEW: barrier-free main loop. No LDS staging at all — each wave streams its
// B-fragments straight from the 1MB L2-resident ws (coalesced 16B/lane) and
// its x scalars straight from X (L1-hot lines reused 16x), software-pipelined
// 2 chunks deep in named registers. LDS used only for the final tree
// reduction. Theory: round-4's bound was barrier-lockstep bubbles (no pipe
// >40%); free-running waves remove them.

#define N_B 32768
#define N_I 512
#define N_O 64

typedef short bf16x8 __attribute__((ext_vector_type(8)));
typedef float f32x4  __attribute__((ext_vector_type(4)));
typedef float f32x16 __attribute__((ext_vector_type(16)));
typedef int   i32x4  __attribute__((ext_vector_type(4)));

// hardware packed f32->bf16 (RNE)
__device__ __forceinline__ int cvtpk(float lo, float hi) {
    int r;
    asm("v_cvt_pk_bf16_f32 %0, %1, %2" : "=v"(r) : "v"(lo), "v"(hi));
    return r;
}

// ---------------- prep: C (f32) -> ws (bf16, fragment-ordered) ----------------
// ws 16B-slot [c*1024 + (q*2+f)*64 + l] = bf16( C[t=l>>5][i=c*8+q][n=f*32+(l&31)][g=0..7] )
__global__ __launch_bounds__(256)
void fkan_prep(const float* __restrict__ C, int4* __restrict__ ws) {
    const int tid = blockIdx.x * 256 + threadIdx.x;   // 65536 threads
    const int t = tid >> 15;
    const int i = (tid >> 6) & 511;
    const int n = tid & 63;
    const float* src = C + ((size_t)(t * N_I + i) * N_O + n) * 8;
    const float4 v0 = *(const float4*)(src);
    const float4 v1 = *(const float4*)(src + 4);
    int4 w;
    w.x = cvtpk(v0.x, v0.y);
    w.y = cvtpk(v0.z, v0.w);
    w.z = cvtpk(v1.x, v1.y);
    w.w = cvtpk(v1.z, v1.w);
    const int c = i >> 3, q = i & 7, f = n >> 5, l = t * 32 + (n & 31);
    ws[c * 1024 + (q * 2 + f) * 64 + l] = w;
}

// ---------------- main ----------------
// branchless cos/sin Chebyshev chain -> packed bf16 A-fragment (freqs 1..8)
__device__ __forceinline__ bf16x8 trigfrag(float x, int h) {
    const float r  = x * 0.15915494309189535f;   // revolutions
    const float s1 = __builtin_amdgcn_sinf(r);
    const float c1 = __builtin_amdgcn_cosf(r);
    const float t2 = c1 + c1;
    const float p0 = h ? 0.f : 1.f;
    const float p1 = h ? s1  : c1;
    const float p2 = __builtin_fmaf(t2, p1, -p0);
    const float p3 = __builtin_fmaf(t2, p2, -p1);
    const float p4 = __builtin_fmaf(t2, p3, -p2);
    const float p5 = __builtin_fmaf(t2, p4, -p3);
    const float p6 = __builtin_fmaf(t2, p5, -p4);
    const float p7 = __builtin_fmaf(t2, p6, -p5);
    const float p8 = __builtin_fmaf(t2, p7, -p6);
    union { int d[4]; bf16x8 v; } u;
    u.d[0] = cvtpk(p1, p2);
    u.d[1] = cvtpk(p3, p4);
    u.d[2] = cvtpk(p5, p6);
    u.d[3] = cvtpk(p7, p8);
    return u.v;
}

// one K-step: 2 B-frags (regs), 2 A-frags (trig), 4 MFMAs
__device__ __forceinline__ void compute4(i32x4 b0r, i32x4 b1r, float xa, float xb,
                                         int h, f32x16* acc) {
    union { i32x4 d; bf16x8 v; } u0, u1;
    u0.d = b0r; u1.d = b1r;
    const bf16x8 A0 = trigfrag(xa, h);
    const bf16x8 A1 = trigfrag(xb, h);
    __builtin_amdgcn_s_setprio(1);
    acc[0] = __builtin_amdgcn_mfma_f32_32x32x16_bf16(A0, u0.v, acc[0], 0, 0, 0);
    acc[1] = __builtin_amdgcn_mfma_f32_32x32x16_bf16(A0, u1.v, acc[1], 0, 0, 0);
    acc[2] = __builtin_amdgcn_mfma_f32_32x32x16_bf16(A1, u0.v, acc[2], 0, 0, 0);
    acc[3] = __builtin_amdgcn_mfma_f32_32x32x16_bf16(A1, u1.v, acc[3], 0, 0, 0);
    __builtin_amdgcn_s_setprio(0);
}

__device__ __forceinline__ void dumpAcc(float* base, const f32x16* acc, int l) {
    #pragma unroll
    for (int fr = 0; fr < 4; ++fr) {
        union { f32x16 v; f32x4 s[4]; } u; u.v = acc[fr];
        #pragma unroll
        for (int rg = 0; rg < 4; ++rg)
            *(f32x4*)(base + fr * 1024 + rg * 256 + l * 4) = u.s[rg];
    }
}
__device__ __forceinline__ void addAcc(const float* base, f32x16* acc, int l) {
    #pragma unroll
    for (int fr = 0; fr < 4; ++fr) {
        union { f32x16 v; f32x4 s[4]; } u; u.v = acc[fr];
        #pragma unroll
        for (int rg = 0; rg < 4; ++rg)
            u.s[rg] += *(const f32x4*)(base + fr * 1024 + rg * 256 + l * 4);
        acc[fr] = u.v;
    }
}

__global__ __launch_bounds__(512, 4)
void fkan_main(const float* __restrict__ X, const int4* __restrict__ Wf,
               const float* __restrict__ bias, float* __restrict__ out) {
    __shared__ __align__(16) float Rsm[16384];   // 64KB, reduction only

    const int tid    = threadIdx.x;
    const int l      = tid & 63;
    const int q      = tid >> 6;     // wave id = K-group (i = c*8 + q)
    const int h      = l >> 5;       // 0: cos, 1: sin
    const int lane31 = l & 31;
    const int row0   = blockIdx.x * 64;

    // per-wave coalesced B stream: slot = c*1024 + q*128 + l (f=0), +64 (f=1)
    const int4* bptr  = Wf + q * 128 + l;
    // per-lane x streams (rows lane31 and lane31+32), chunk c at +c*8 floats
    const float* xa_p = X + (size_t)(row0 + lane31) * N_I + q;
    const float* xb_p = xa_p + 32 * N_I;

    f32x16 acc[4];
    #pragma unroll
    for (int a = 0; a < 4; ++a)
        #pragma unroll
        for (int r = 0; r < 16; ++r) acc[a][r] = 0.f;

    // ---- prologue: load chunks 0 (slot A) and 1 (slot B) ----
    i32x4 a_b0 = *(const i32x4*)(bptr);
    i32x4 a_b1 = *(const i32x4*)(bptr + 64);
    float a_xa = xa_p[0];
    float a_xb = xb_p[0];
    i32x4 c_b0 = *(const i32x4*)(bptr + 1024);
    i32x4 c_b1 = *(const i32x4*)(bptr + 1024 + 64);
    float c_xa = xa_p[8];
    float c_xb = xb_p[8];

    // ---- barrier-free main loop, 2 chunks/iter, 2-deep reg pipeline ----
    #pragma unroll 1
    for (int c = 0; c < 64; c += 2) {
        const int cp = (c + 2 <= 63) ? (c + 2) : 63;   // even slot prefetch
        const int cq = (c + 3 <= 63) ? (c + 3) : 63;   // odd slot prefetch

        // chunk c (slot A), then refill slot A with chunk c+2
        compute4(a_b0, a_b1, a_xa, a_xb, h, acc);
        {
            const int4* bp = bptr + (size_t)cp * 1024;
            a_b0 = *(const i32x4*)bp;
            a_b1 = *(const i32x4*)(bp + 64);
            a_xa = xa_p[cp * 8];
            a_xb = xb_p[cp * 8];
        }

        // chunk c+1 (slot B), then refill slot B with chunk c+3
        compute4(c_b0, c_b1, c_xa, c_xb, h, acc);
        {
            const int4* bp = bptr + (size_t)cq * 1024;
            c_b0 = *(const i32x4*)bp;
            c_b1 = *(const i32x4*)(bp + 64);
            c_xa = xa_p[cq * 8];
            c_xb = xb_p[cq * 8];
        }
    }

    __syncthreads();

    // ---- 3-phase tree reduction over K-groups (8 -> 4 -> 2 -> 1) ----
    float* R = Rsm;
    if (q >= 4) dumpAcc(R + (q - 4) * 4096, acc, l);
    __syncthreads();
    if (q < 4) addAcc(R + q * 4096, acc, l);
    __syncthreads();
    if (q == 2 || q == 3) dumpAcc(R + (q - 2) * 4096, acc, l);
    __syncthreads();
    if (q < 2) addAcc(R + q * 4096, acc, l);
    __syncthreads();
    if (q == 1) dumpAcc(R, acc, l);
    __syncthreads();
    if (q == 0) {
        addAcc(R, acc, l);
        #pragma unroll
        for (int mt = 0; mt < 2; ++mt) {
            #pragma unroll
            for (int f = 0; f < 2; ++f) {
                const float bv = bias[f * 32 + lane31];
                #pragma unroll
                for (int r = 0; r < 16; ++r) {
                    const int orow = mt * 32 + (r & 3) + 8 * (r >> 2) + 4 * h;
                    out[(size_t)(row0 + orow) * N_O + f * 32 + lane31] =
                        acc[mt * 2 + f][r] + bv;
                }
            }
        }
    }
}

extern "C" void kernel_launch(void* const* d_in, const int* in_sizes, int n_in,
                              void* d_out, int out_size, void* d_ws, size_t ws_size,
                              hipStream_t stream) {
    const float* X    = (const float*)d_in[0];   // (32768, 512) f32
    const float* C    = (const float*)d_in[1];   // (2, 512, 64, 8) f32
    const float* bias = (const float*)d_in[2];   // (64,) f32
    float* out = (float*)d_out;                  // (32768, 64) f32
    int4* ws = (int4*)d_ws;                      // 1 MB bf16 fragment-ordered weights

    fkan_prep<<<256, 256, 0, stream>>>(C, ws);
    fkan_main<<<512, 512, 0, stream>>>(X, ws, bias, out);
}